// Round 1
// baseline (654.821 us; speedup 1.0000x reference)
//
#include <hip/hip_runtime.h>

typedef unsigned short ushort_t;
typedef __attribute__((ext_vector_type(8))) short short8;
typedef __attribute__((ext_vector_type(4))) float f32x4;

#define TOKENS  4096
#define H_DIM   1024
#define HFF_DIM 4096
#define NEXP    8

// round-to-nearest-even f32 -> bf16
__device__ __forceinline__ ushort_t f2b(float f) {
    union { float f; unsigned u; } v; v.f = f;
    unsigned r = v.u + 0x7fffu + ((v.u >> 16) & 1u);
    return (ushort_t)(r >> 16);
}

// jax.nn.gelu default: approximate=True (tanh form)
__device__ __forceinline__ float gelu_tanh(float x) {
    float u = 0.7978845608028654f * (x + 0.044715f * x * x * x);
    return 0.5f * x * (1.0f + tanhf(u));
}

// ---------------- routing ----------------
__global__ void route_kernel(const float* __restrict__ probs,
                             const int* __restrict__ idx,
                             int* __restrict__ count,
                             int* __restrict__ token_id,
                             float* __restrict__ gate) {
    int t = blockIdx.x * blockDim.x + threadIdx.x;
    if (t >= TOKENS) return;
    int i0 = idx[t * 2 + 0];
    int i1 = idx[t * 2 + 1];
    float p0 = probs[t * 2 + 0];
    float p1 = probs[t * 2 + 1];
    if (i0 == i1) {
        float p = fmaxf(p0, p1);
        int pos = atomicAdd(&count[i0], 1);
        token_id[i0 * TOKENS + pos] = t;
        gate[i0 * TOKENS + pos] = p;
    } else {
        int pos = atomicAdd(&count[i0], 1);
        token_id[i0 * TOKENS + pos] = t;
        gate[i0 * TOKENS + pos] = p0;
        pos = atomicAdd(&count[i1], 1);
        token_id[i1 * TOKENS + pos] = t;
        gate[i1 * TOKENS + pos] = p1;
    }
}

__global__ void prefix_kernel(const int* __restrict__ count, int* __restrict__ offsets) {
    if (threadIdx.x == 0 && blockIdx.x == 0) {
        int acc = 0;
        for (int e = 0; e < NEXP; ++e) { offsets[e] = acc; acc += count[e]; }
        offsets[NEXP] = acc;
    }
}

// ---------------- GEMM1: h[row] = gelu(x[tok] . W1[e]^T), bf16 out ----------------
// tile 128x128, BK=32, 256 threads (4 waves, 2x2 of 64x64 each)
__global__ __launch_bounds__(256) void gemm1_kernel(
        const float* __restrict__ x, const float* __restrict__ W1,
        const int* __restrict__ count, const int* __restrict__ offsets,
        const int* __restrict__ token_id, ushort_t* __restrict__ h) {
    const int e = blockIdx.z;
    const int cnt = count[e];
    const int mt = blockIdx.y;
    if (mt * 128 >= cnt) return;
    const int nt = blockIdx.x;
    const int base = offsets[e];

    __shared__ __align__(16) ushort_t As[128 * 32];
    __shared__ __align__(16) ushort_t Bs[128 * 32];

    const int tid = threadIdx.x;
    const int srow = tid >> 1;
    const int scol = (tid & 1) << 4;

    int am = mt * 128 + srow;
    int amc = am < cnt ? am : (cnt - 1);          // clamp: garbage rows unused
    const int tok = token_id[e * TOKENS + amc];
    const float* aptr = x + (size_t)tok * H_DIM + scol;
    const float* bptr = W1 + (size_t)e * HFF_DIM * H_DIM
                        + (size_t)(nt * 128 + srow) * H_DIM + scol;

    const int lane = tid & 63;
    const int wave = tid >> 6;
    const int wm = (wave >> 1) << 6;
    const int wn = (wave & 1) << 6;
    const int lr = lane & 15;
    const int lq = lane >> 4;

    f32x4 acc[4][4];
#pragma unroll
    for (int mi = 0; mi < 4; ++mi)
#pragma unroll
        for (int ni = 0; ni < 4; ++ni)
            acc[mi][ni] = (f32x4){0.f, 0.f, 0.f, 0.f};

    for (int k0 = 0; k0 < H_DIM; k0 += 32) {
        ushort_t ta[16], tb[16];
        const float4* pa = (const float4*)(aptr + k0);
        const float4* pb = (const float4*)(bptr + k0);
#pragma unroll
        for (int i = 0; i < 4; ++i) {
            float4 va = pa[i];
            ta[i * 4 + 0] = f2b(va.x); ta[i * 4 + 1] = f2b(va.y);
            ta[i * 4 + 2] = f2b(va.z); ta[i * 4 + 3] = f2b(va.w);
            float4 vb = pb[i];
            tb[i * 4 + 0] = f2b(vb.x); tb[i * 4 + 1] = f2b(vb.y);
            tb[i * 4 + 2] = f2b(vb.z); tb[i * 4 + 3] = f2b(vb.w);
        }
        __syncthreads();
        *(short8*)&As[srow * 32 + scol]     = *(short8*)&ta[0];
        *(short8*)&As[srow * 32 + scol + 8] = *(short8*)&ta[8];
        *(short8*)&Bs[srow * 32 + scol]     = *(short8*)&tb[0];
        *(short8*)&Bs[srow * 32 + scol + 8] = *(short8*)&tb[8];
        __syncthreads();

        short8 af[4], bf[4];
#pragma unroll
        for (int mi = 0; mi < 4; ++mi)
            af[mi] = *(const short8*)&As[(wm + mi * 16 + lr) * 32 + lq * 8];
#pragma unroll
        for (int ni = 0; ni < 4; ++ni)
            bf[ni] = *(const short8*)&Bs[(wn + ni * 16 + lr) * 32 + lq * 8];
#pragma unroll
        for (int mi = 0; mi < 4; ++mi)
#pragma unroll
            for (int ni = 0; ni < 4; ++ni)
                acc[mi][ni] = __builtin_amdgcn_mfma_f32_16x16x32_bf16(
                    af[mi], bf[ni], acc[mi][ni], 0, 0, 0);
    }

    // epilogue: gelu -> bf16 h
#pragma unroll
    for (int mi = 0; mi < 4; ++mi) {
#pragma unroll
        for (int r = 0; r < 4; ++r) {
            int m = mt * 128 + wm + mi * 16 + lq * 4 + r;
            if (m < cnt) {
                ushort_t* hp = h + (size_t)(base + m) * HFF_DIM + nt * 128 + wn + lr;
#pragma unroll
                for (int ni = 0; ni < 4; ++ni)
                    hp[ni * 16] = f2b(gelu_tanh(acc[mi][ni][r]));
            }
        }
    }
}

// ---------------- GEMM2: out[tok] += gate * (h[row] . W2[e]^T) ----------------
__global__ __launch_bounds__(256) void gemm2_kernel(
        const ushort_t* __restrict__ h, const float* __restrict__ W2,
        const int* __restrict__ count, const int* __restrict__ offsets,
        const int* __restrict__ token_id, const float* __restrict__ gate,
        float* __restrict__ out) {
    const int e = blockIdx.z;
    const int cnt = count[e];
    const int mt = blockIdx.y;
    if (mt * 128 >= cnt) return;
    const int nt = blockIdx.x;
    const int base = offsets[e];

    __shared__ __align__(16) ushort_t As[128 * 32];
    __shared__ __align__(16) ushort_t Bs[128 * 32];

    const int tid = threadIdx.x;
    const int srow = tid >> 1;
    const int scol = (tid & 1) << 4;

    int am = mt * 128 + srow;
    int amc = am < cnt ? am : (cnt - 1);
    const ushort_t* aptr = h + (size_t)(base + amc) * HFF_DIM + scol;
    const float* bptr = W2 + (size_t)e * H_DIM * HFF_DIM
                        + (size_t)(nt * 128 + srow) * HFF_DIM + scol;

    const int lane = tid & 63;
    const int wave = tid >> 6;
    const int wm = (wave >> 1) << 6;
    const int wn = (wave & 1) << 6;
    const int lr = lane & 15;
    const int lq = lane >> 4;

    f32x4 acc[4][4];
#pragma unroll
    for (int mi = 0; mi < 4; ++mi)
#pragma unroll
        for (int ni = 0; ni < 4; ++ni)
            acc[mi][ni] = (f32x4){0.f, 0.f, 0.f, 0.f};

    for (int k0 = 0; k0 < HFF_DIM; k0 += 32) {
        short8 a0 = *(const short8*)(aptr + k0);
        short8 a1 = *(const short8*)(aptr + k0 + 8);
        ushort_t tb[16];
        const float4* pb = (const float4*)(bptr + k0);
#pragma unroll
        for (int i = 0; i < 4; ++i) {
            float4 vb = pb[i];
            tb[i * 4 + 0] = f2b(vb.x); tb[i * 4 + 1] = f2b(vb.y);
            tb[i * 4 + 2] = f2b(vb.z); tb[i * 4 + 3] = f2b(vb.w);
        }
        __syncthreads();
        *(short8*)&As[srow * 32 + scol]     = a0;
        *(short8*)&As[srow * 32 + scol + 8] = a1;
        *(short8*)&Bs[srow * 32 + scol]     = *(short8*)&tb[0];
        *(short8*)&Bs[srow * 32 + scol + 8] = *(short8*)&tb[8];
        __syncthreads();

        short8 af[4], bf[4];
#pragma unroll
        for (int mi = 0; mi < 4; ++mi)
            af[mi] = *(const short8*)&As[(wm + mi * 16 + lr) * 32 + lq * 8];
#pragma unroll
        for (int ni = 0; ni < 4; ++ni)
            bf[ni] = *(const short8*)&Bs[(wn + ni * 16 + lr) * 32 + lq * 8];
#pragma unroll
        for (int mi = 0; mi < 4; ++mi)
#pragma unroll
            for (int ni = 0; ni < 4; ++ni)
                acc[mi][ni] = __builtin_amdgcn_mfma_f32_16x16x32_bf16(
                    af[mi], bf[ni], acc[mi][ni], 0, 0, 0);
    }

    // epilogue: scale by gate, scatter-add into out
#pragma unroll
    for (int mi = 0; mi < 4; ++mi) {
#pragma unroll
        for (int r = 0; r < 4; ++r) {
            int m = mt * 128 + wm + mi * 16 + lq * 4 + r;
            if (m < cnt) {
                int tok = token_id[e * TOKENS + m];
                float g = gate[e * TOKENS + m];
                float* op = out + (size_t)tok * H_DIM + nt * 128 + wn + lr;
#pragma unroll
                for (int ni = 0; ni < 4; ++ni)
                    atomicAdd(&op[ni * 16], g * acc[mi][ni][r]);
            }
        }
    }
}

extern "C" void kernel_launch(void* const* d_in, const int* in_sizes, int n_in,
                              void* d_out, int out_size, void* d_ws, size_t ws_size,
                              hipStream_t stream) {
    const float* x     = (const float*)d_in[0];
    const float* probs = (const float*)d_in[1];
    const int*   idx   = (const int*)d_in[2];
    const float* W1    = (const float*)d_in[3];
    const float* W2    = (const float*)d_in[4];
    float* out = (float*)d_out;

    char* ws = (char*)d_ws;
    int*      count    = (int*)ws;                               // 8 ints
    int*      offsets  = (int*)(ws + 64);                        // 9 ints
    int*      token_id = (int*)(ws + 4096);                      // 8*4096 ints (128 KB)
    float*    gate     = (float*)(ws + 4096 + 8 * 4096 * 4);     // 128 KB
    ushort_t* h        = (ushort_t*)(ws + (1 << 20));            // 8192*4096 bf16 = 64 MB

    hipMemsetAsync(count, 0, 64, stream);
    hipMemsetAsync(out, 0, (size_t)out_size * sizeof(float), stream);

    route_kernel<<<TOKENS / 256, 256, 0, stream>>>(probs, idx, count, token_id, gate);
    prefix_kernel<<<1, 64, 0, stream>>>(count, offsets);

    dim3 g1(HFF_DIM / 128, TOKENS / 128, NEXP);
    gemm1_kernel<<<g1, 256, 0, stream>>>(x, W1, count, offsets, token_id, h);

    dim3 g2(H_DIM / 128, TOKENS / 128, NEXP);
    gemm2_kernel<<<g2, 256, 0, stream>>>(h, W2, count, offsets, token_id, gate, out);
}